// Round 8
// baseline (508.133 us; speedup 1.0000x reference)
//
#include <hip/hip_runtime.h>

#define NN 50000
#define HECNT 10000
#define EE 800000
#define II 800000
#define NBK 128          // buckets per task (counting sort)
#define CHUNK 4096       // edges per workgroup in bin kernels
#define BKCAP 8192       // fixed staging capacity per bucket (mean 6250, +24 sigma)

typedef _Float16 half8 __attribute__((ext_vector_type(8)));
typedef float f32x4    __attribute__((ext_vector_type(4)));
typedef unsigned short u16;

__device__ __forceinline__ int ld_idx(const int* p, long long pos, int is64) {
    return is64 ? p[pos * 2] : p[(int)pos];
}

__device__ __forceinline__ void task_info(int t, int& n, int& cbase, int& obase) {
    if (t == 0)      { n = HECNT; cbase = 0;           obase = 0; }
    else if (t == 1) { n = NN;    cbase = HECNT;       obase = HECNT + 1; }
    else             { n = NN;    cbase = HECNT + NN;  obase = HECNT + NN + 2; }
}

// ---------------- detect index width + init bucket cursors ----------------
__global__ void detect_binit_k(const int* __restrict__ EIX, const int* __restrict__ HIX,
                               int* __restrict__ flags, int* __restrict__ bcur) {
    int tid = threadIdx.x;
    int i = blockIdx.x * 256 + tid;
    if (i < 3 * NBK) bcur[i] = i * BKCAP;
    if (blockIdx.x == 0) {
        __shared__ int o0, o1;
        if (tid == 0) { o0 = 0; o1 = 0; }
        __syncthreads();
        atomicOr(&o0, EIX[2 * tid + 1]);
        atomicOr(&o1, HIX[2 * tid + 1]);
        __syncthreads();
        if (tid == 0) { flags[0] = (o0 == 0); flags[1] = (o1 == 0); }
    }
}

// ---- bin tasks 0 & 1 in ONE pass over HIX (shared index loads) ----
__global__ __launch_bounds__(256) void bin01_k(const int* __restrict__ HIX,
                                               const int* __restrict__ flags,
                                               int* __restrict__ bcur,
                                               unsigned* __restrict__ pairs) {
    __shared__ int hcnt[2][NBK], hstart[2][NBK], hrun[2][NBK], gbase[2][NBK];
    __shared__ int stot[2];
    __shared__ unsigned stage[2][CHUNK];    // 32 KB
    int tid = threadIdx.x;
    long long base = (long long)blockIdx.x * CHUNK;
    int f1 = flags[1];
    const int span0 = (HECNT + NBK - 1) / NBK;   // 79
    const int span1 = (NN + NBK - 1) / NBK;      // 391

    for (int i = tid; i < NBK; i += 256) {
        hcnt[0][i] = 0; hcnt[1][i] = 0; hrun[0][i] = 0; hrun[1][i] = 0;
    }
    __syncthreads();

    int nd[16], he[16];
    #pragma unroll
    for (int j = 0; j < 16; j++) {
        long long i = base + j * 256 + tid;
        int n_ = -1, h_ = -1;
        if (i < II) {
            n_ = ld_idx(HIX, i, f1);
            h_ = ld_idx(HIX, (long long)II + i, f1);
            if ((unsigned)n_ >= (unsigned)NN || (unsigned)h_ >= (unsigned)HECNT) { n_ = -1; h_ = -1; }
        }
        nd[j] = n_; he[j] = h_;
        if (h_ >= 0) { atomicAdd(&hcnt[0][h_ / span0], 1); atomicAdd(&hcnt[1][n_ / span1], 1); }
    }
    __syncthreads();

    if (tid < NBK) {
        gbase[0][tid] = hcnt[0][tid] ? atomicAdd(&bcur[tid], hcnt[0][tid]) : 0;
        gbase[1][tid] = hcnt[1][tid] ? atomicAdd(&bcur[NBK + tid], hcnt[1][tid]) : 0;
        hstart[0][tid] = hcnt[0][tid];
        hstart[1][tid] = hcnt[1][tid];
    }
    __syncthreads();
    for (int o = 1; o < NBK; o <<= 1) {
        int u0 = 0, u1 = 0;
        if (tid < NBK && tid >= o) { u0 = hstart[0][tid - o]; u1 = hstart[1][tid - o]; }
        __syncthreads();
        if (tid < NBK) { hstart[0][tid] += u0; hstart[1][tid] += u1; }
        __syncthreads();
    }
    if (tid == NBK - 1) { stot[0] = hstart[0][tid]; stot[1] = hstart[1][tid]; }
    __syncthreads();
    if (tid < NBK) { hstart[0][tid] -= hcnt[0][tid]; hstart[1][tid] -= hcnt[1][tid]; }
    __syncthreads();

    #pragma unroll
    for (int j = 0; j < 16; j++) {
        if (he[j] >= 0) {
            int b0 = he[j] / span0;
            int p0 = hstart[0][b0] + atomicAdd(&hrun[0][b0], 1);
            stage[0][p0] = ((unsigned)he[j] << 16) | (unsigned)nd[j];
            int b1 = nd[j] / span1;
            int p1 = hstart[1][b1] + atomicAdd(&hrun[1][b1], 1);
            stage[1][p1] = ((unsigned)nd[j] << 16) | (unsigned)he[j];
        }
    }
    __syncthreads();

    for (int tt = 0; tt < 2; tt++) {
        int total = stot[tt];
        for (int i = tid; i < total; i += 256) {
            int lo = 0, hi = NBK - 1;
            while (lo < hi) { int mid = (lo + hi + 1) >> 1; if (hstart[tt][mid] <= i) lo = mid; else hi = mid - 1; }
            int pos = gbase[tt][lo] + (i - hstart[tt][lo]);
            if (pos < (tt * NBK + lo + 1) * BKCAP)
                pairs[pos] = stage[tt][i];
        }
    }
}

// ---- bin task 2 (graph edges, dest = e_dst) ----
__global__ __launch_bounds__(256) void bin2_k(const int* __restrict__ EIX,
                                              const int* __restrict__ flags,
                                              int* __restrict__ bcur,
                                              unsigned* __restrict__ pairs) {
    __shared__ int hcnt[NBK], hstart[NBK], hrun[NBK], gbase[NBK];
    __shared__ int stot;
    __shared__ unsigned stage[CHUNK];    // 16 KB
    int tid = threadIdx.x;
    long long base = (long long)blockIdx.x * CHUNK;
    int f0 = flags[0];
    const int span = (NN + NBK - 1) / NBK;   // 391

    for (int i = tid; i < NBK; i += 256) { hcnt[i] = 0; hrun[i] = 0; }
    __syncthreads();

    int d[16], v[16];
    #pragma unroll
    for (int j = 0; j < 16; j++) {
        long long i = base + j * 256 + tid;
        int dd = -1, vv = -1;
        if (i < EE) {
            dd = ld_idx(EIX, (long long)EE + i, f0);
            vv = ld_idx(EIX, i, f0);
            if ((unsigned)dd >= (unsigned)NN || (unsigned)vv >= (unsigned)NN) dd = -1;
        }
        d[j] = dd; v[j] = vv;
        if (dd >= 0) atomicAdd(&hcnt[dd / span], 1);
    }
    __syncthreads();

    if (tid < NBK) gbase[tid] = hcnt[tid] ? atomicAdd(&bcur[2 * NBK + tid], hcnt[tid]) : 0;
    if (tid < NBK) hstart[tid] = hcnt[tid];
    __syncthreads();
    for (int o = 1; o < NBK; o <<= 1) {
        int u = 0;
        if (tid < NBK && tid >= o) u = hstart[tid - o];
        __syncthreads();
        if (tid < NBK) hstart[tid] += u;
        __syncthreads();
    }
    if (tid == NBK - 1) stot = hstart[tid];
    __syncthreads();
    if (tid < NBK) hstart[tid] -= hcnt[tid];
    __syncthreads();

    #pragma unroll
    for (int j = 0; j < 16; j++) {
        if (d[j] >= 0) {
            int b = d[j] / span;
            int p = hstart[b] + atomicAdd(&hrun[b], 1);
            stage[p] = ((unsigned)d[j] << 16) | (unsigned)v[j];
        }
    }
    __syncthreads();

    int total = stot;
    for (int i = tid; i < total; i += 256) {
        int lo = 0, hi = NBK - 1;
        while (lo < hi) { int mid = (lo + hi + 1) >> 1; if (hstart[mid] <= i) lo = mid; else hi = mid - 1; }
        int pos = gbase[lo] + (i - hstart[lo]);
        if (pos < (2 * NBK + lo + 1) * BKCAP)
            pairs[pos] = stage[i];
    }
}

// per-bucket dest histogram from staged pairs — LDS atomics only, coalesced writes
__global__ __launch_bounds__(256) void count_k(const int* __restrict__ bcur,
                                               const unsigned* __restrict__ pairs,
                                               int* __restrict__ counts) {
    int idx = blockIdx.x;              // 0 .. 3*NBK-1
    int t = idx / NBK, b = idx % NBK;
    int n, cb, ob; task_info(t, n, cb, ob);
    int span = (n + NBK - 1) / NBK;
    int dlo = min(b * span, n), dhi = min(dlo + span, n);
    __shared__ int hist[400];
    int tid = threadIdx.x;
    for (int i = tid; i < dhi - dlo; i += 256) hist[i] = 0;
    __syncthreads();
    int cnt = min(bcur[idx] - idx * BKCAP, BKCAP);
    const unsigned* pw = pairs + (size_t)idx * BKCAP;
    for (int i = tid; i < cnt; i += 256) {
        int dl = (int)(pw[i] >> 16) - dlo;
        if ((unsigned)dl < (unsigned)(dhi - dlo)) atomicAdd(&hist[dl], 1);
    }
    __syncthreads();
    for (int i = tid; i < dhi - dlo; i += 256) counts[cb + dlo + i] = hist[i];
}

__global__ __launch_bounds__(256) void scan_p1(const int* __restrict__ counts,
                                               int* __restrict__ bsums) {
    int t = blockIdx.y;
    int n, cb, ob; task_info(t, n, cb, ob);
    int base = blockIdx.x * 1024 + threadIdx.x * 4;
    int s = 0;
    #pragma unroll
    for (int j = 0; j < 4; j++) { int i = base + j; if (i < n) s += counts[cb + i]; }
    __shared__ int red[256];
    red[threadIdx.x] = s; __syncthreads();
    for (int o = 128; o > 0; o >>= 1) {
        if (threadIdx.x < o) red[threadIdx.x] += red[threadIdx.x + o];
        __syncthreads();
    }
    if (threadIdx.x == 0) bsums[t * 64 + blockIdx.x] = red[0];
}

__global__ void scan_p2(int* __restrict__ bsums, int* __restrict__ offs) {
    int t = blockIdx.y;
    int n, cb, ob; task_info(t, n, cb, ob);
    int lane = threadIdx.x;
    int nb = (n + 1023) / 1024;
    int v = (lane < nb) ? bsums[t * 64 + lane] : 0;
    int incl = v;
    for (int d = 1; d < 64; d <<= 1) {
        int u = __shfl_up(incl, (unsigned)d, 64);
        if (lane >= d) incl += u;
    }
    bsums[t * 64 + lane] = incl - v;           // exclusive block sums
    int total = __shfl(incl, 63, 64);
    if (lane == 0) offs[ob + n] = total;
}

__global__ __launch_bounds__(256) void scan_p3(const int* __restrict__ counts,
                                               const int* __restrict__ bsums,
                                               int* __restrict__ offs) {
    int t = blockIdx.y;
    int n, cb, ob; task_info(t, n, cb, ob);
    int tid = threadIdx.x;
    int base = blockIdx.x * 1024 + tid * 4;
    int c[4]; int s = 0;
    #pragma unroll
    for (int j = 0; j < 4; j++) { int i = base + j; c[j] = (i < n) ? counts[cb + i] : 0; s += c[j]; }
    __shared__ int sc[256];
    sc[tid] = s; __syncthreads();
    for (int o = 1; o < 256; o <<= 1) {
        int v = (tid >= o) ? sc[tid - o] : 0;
        __syncthreads();
        sc[tid] += v;
        __syncthreads();
    }
    int excl = sc[tid] - s;
    int p = bsums[t * 64 + blockIdx.x] + excl;
    #pragma unroll
    for (int j = 0; j < 4; j++) {
        int i = base + j;
        if (i < n) { offs[ob + i] = p; p += c[j]; }
    }
}

// per-bucket exact CSR placement via LDS window, coalesced u16 flush
__global__ __launch_bounds__(256) void unbin_k(const int* __restrict__ offs,
                                               const unsigned* __restrict__ pairs,
                                               u16* __restrict__ vals) {
    int idx = blockIdx.x;              // 0 .. 3*NBK-1
    int t = idx / NBK, b = idx % NBK;
    int n, cb, ob; task_info(t, n, cb, ob);
    int span = (n + NBK - 1) / NBK;
    int dlo = min(b * span, n), dhi = min(dlo + span, n);
    if (dhi <= dlo) return;
    int p0 = offs[ob + dlo], p1 = offs[ob + dhi];
    int cnt = p1 - p0;                 // == staged count (counts derived from staging)
    __shared__ u16 win[BKCAP];         // 16 KB
    __shared__ int cur[400];
    int tid = threadIdx.x;
    for (int i = tid; i < dhi - dlo; i += 256) cur[i] = offs[ob + dlo + i] - p0;
    __syncthreads();
    const unsigned* pw = pairs + (size_t)idx * BKCAP;
    u16* vw = vals + (size_t)t * 800000 + p0;
    if (cnt > BKCAP) cnt = BKCAP;
    for (int i = tid; i < cnt; i += 256) {
        unsigned pv = pw[i];
        int dl = (int)(pv >> 16) - dlo;
        if ((unsigned)dl < (unsigned)(dhi - dlo)) {
            int p = atomicAdd(&cur[dl], 1);
            if ((unsigned)p < (unsigned)BKCAP) win[p] = (u16)(pv & 0xffffu);
        }
    }
    __syncthreads();
    for (int i = tid; i < cnt; i += 256) vw[i] = win[i];
}

// ------- gather: 1 dest/wave, 16 lanes x half8, 16 rows in flight/wave; epilogue finishes the layer -------
__global__ __launch_bounds__(256) void gather_k(const int* __restrict__ offs,
                                                const u16* __restrict__ vals,
                                                const _Float16* __restrict__ src,   // [S x 128] f16
                                                _Float16* __restrict__ out,         // [ndst x 128] f16
                                                int ndst, int nsrc, int scale_flag,
                                                const float* __restrict__ bias,
                                                const _Float16* __restrict__ addend,
                                                int act) {
    int wave = threadIdx.x >> 6, lane = threadIdx.x & 63;
    int sub = lane >> 4, l16 = lane & 15;
    int d = blockIdx.x * 4 + wave;
    if (d >= ndst) return;
    int beg = offs[d], end = offs[d + 1];
    int f = l16 * 8;
    float a[8] = {0.f, 0.f, 0.f, 0.f, 0.f, 0.f, 0.f, 0.f};
    auto acc_row = [&](int s) {
        if ((unsigned)s < (unsigned)nsrc) {
            half8 u = *(const half8*)(src + (size_t)s * 128 + f);
            #pragma unroll
            for (int j = 0; j < 8; j++) a[j] += (float)u[j];
        }
    };
    int e = beg + sub;
    for (; e + 12 < end; e += 16) {          // 4 rows in flight per sub, 16 per wave
        int s0 = vals[e], s1 = vals[e + 4], s2 = vals[e + 8], s3 = vals[e + 12];
        acc_row(s0); acc_row(s1); acc_row(s2); acc_row(s3);
    }
    for (; e < end; e += 4) acc_row(vals[e]);
    #pragma unroll
    for (int j = 0; j < 8; j++) {
        a[j] += __shfl_xor(a[j], 16, 64);
        a[j] += __shfl_xor(a[j], 32, 64);
    }
    if (sub == 0) {
        if (scale_flag) {
            int c = end - beg;
            float iv = (c > 0) ? 1.f / (float)c : 0.f;
            #pragma unroll
            for (int j = 0; j < 8; j++) a[j] *= iv;
        }
        if (bias) {
            f32x4 b0 = *(const f32x4*)(bias + f);
            f32x4 b1 = *(const f32x4*)(bias + f + 4);
            #pragma unroll
            for (int j = 0; j < 4; j++) { a[j] += b0[j]; a[4 + j] += b1[j]; }
        }
        if (addend) {
            half8 u = *(const half8*)(addend + (size_t)d * 128 + f);
            #pragma unroll
            for (int j = 0; j < 8; j++) a[j] += (float)u[j];
        }
        if (act) {
            #pragma unroll
            for (int j = 0; j < 8; j++) a[j] = (a[j] >= 0.f) ? a[j] : 0.01f * a[j];
        }
        half8 o;
        #pragma unroll
        for (int j = 0; j < 8; j++) o[j] = (_Float16)a[j];
        *(half8*)(out + (size_t)d * 128 + f) = o;
    }
}

// ---- one-time weight prep: write W in MFMA B-fragment order (half8 per lane) ----
__global__ __launch_bounds__(256) void wprep_k(const float* __restrict__ hc1_w, const float* __restrict__ lin1_w,
                                               const float* __restrict__ hc2_w, const float* __restrict__ lin2_w,
                                               const float* __restrict__ c1_wrel, const float* __restrict__ c1_wroot,
                                               const float* __restrict__ glin1_w,
                                               const float* __restrict__ c2_wrel, const float* __restrict__ c2_wroot,
                                               const float* __restrict__ glin2_w,
                                               const float* __restrict__ fc_w,
                                               _Float16* __restrict__ F) {
    int set = blockIdx.y;
    int nfrag = (set == 4) ? 1024 : 4096;   // # of half8 fragments
    int NT = (set < 2) ? 16 : (set == 4 ? 4 : 8);
    int fid = blockIdx.x * 256 + threadIdx.x;
    if (fid >= nfrag) return;
    int lane = fid & 63;
    int tile = fid >> 6;                    // ks*NT + nt
    int nt = tile % NT, ks = tile / NT;
    int n = nt * 16 + (lane & 15);
    int kbase = ks * 32 + (lane >> 4) * 8;
    _Float16* dst = F + (size_t)set * 32768 + (size_t)fid * 8;
    #pragma unroll
    for (int j = 0; j < 8; j++) {
        int k = kbase + j;
        float w;
        if (set == 0)      w = (n < 128) ? hc1_w[k * 128 + n] : lin1_w[k * 128 + n - 128];
        else if (set == 1) w = (n < 128) ? hc2_w[k * 128 + n] : lin2_w[k * 128 + n - 128];
        else if (set == 2) w = (k < 128) ? c1_wrel[k * 128 + n]
                                         : c1_wroot[(k - 128) * 128 + n] + glin1_w[(k - 128) * 128 + n];
        else if (set == 3) w = (k < 128) ? c2_wrel[k * 128 + n]
                                         : c2_wroot[(k - 128) * 128 + n] + glin2_w[(k - 128) * 128 + n];
        else               w = fc_w[k * 64 + n];
        dst[j] = (_Float16)w;
    }
}

// ---- dual-output GEMM, LDS-free: P = A@W1, L = A@W2 + b2. B-frags from global (L2-hot). ----
template <typename AT>
__global__ __launch_bounds__(256) void gemm2_k(const AT* __restrict__ A,
                                               const half8* __restrict__ Bf,   // KS=4, NT=16
                                               const float* __restrict__ b2,
                                               _Float16* __restrict__ O1,
                                               _Float16* __restrict__ O2,
                                               int M) {
    constexpr int K = 128, NT = 16;
    int tid = threadIdx.x;
    int wave = tid >> 6, lane = tid & 63;
    int quad = lane >> 4, l16 = lane & 15;
    int rowbase = blockIdx.x * 64 + wave * 16;
    int row = rowbase + l16;

    f32x4 acc[NT];
    f32x4 zero4 = {0.f, 0.f, 0.f, 0.f};
    #pragma unroll
    for (int nt = 0; nt < NT; nt++) acc[nt] = zero4;

    #pragma unroll
    for (int ks = 0; ks < 4; ks++) {
        int k0 = ks * 32 + quad * 8;
        half8 af = {0, 0, 0, 0, 0, 0, 0, 0};
        if (row < M) {
            if constexpr (sizeof(AT) == 4) {
                const float* ap = (const float*)A + (size_t)row * K + k0;
                float4 x0 = *(const float4*)ap;
                float4 x1 = *(const float4*)(ap + 4);
                af = half8{(_Float16)x0.x, (_Float16)x0.y, (_Float16)x0.z, (_Float16)x0.w,
                           (_Float16)x1.x, (_Float16)x1.y, (_Float16)x1.z, (_Float16)x1.w};
            } else {
                af = *(const half8*)((const _Float16*)A + (size_t)row * K + k0);
            }
        }
        #pragma unroll
        for (int nt = 0; nt < NT; nt++) {
            half8 bfr = Bf[(ks * NT + nt) * 64 + lane];
            acc[nt] = __builtin_amdgcn_mfma_f32_16x16x32_f16(af, bfr, acc[nt], 0, 0, 0);
        }
    }

    #pragma unroll
    for (int nt = 0; nt < NT; nt++) {
        int col = nt * 16 + l16;
        bool second = (col >= 128);
        int c = second ? col - 128 : col;
        float bv = second ? b2[c] : 0.f;
        _Float16* O = second ? O2 : O1;
        #pragma unroll
        for (int r = 0; r < 4; r++) {
            int rr = rowbase + quad * 4 + r;
            if (rr < M) O[(size_t)rr * 128 + c] = (_Float16)(acc[nt][r] + bv);
        }
    }
}

// ---- K=256 GEMM, LDS-free: out = leaky(A0@Wrel + A1@(Wroot+Wlin) + brel + blin) ----
__global__ __launch_bounds__(256) void gemmk2_k(const _Float16* __restrict__ A0,
                                                const _Float16* A1,
                                                const half8* __restrict__ Bf,   // KS=8, NT=8
                                                const float* __restrict__ brel,
                                                const float* __restrict__ blin,
                                                float* __restrict__ Cf,    // optional f32 out
                                                _Float16* Ch,              // f16 out (may alias A1)
                                                int M) {
    constexpr int NT = 8;
    int tid = threadIdx.x;
    int wave = tid >> 6, lane = tid & 63;
    int quad = lane >> 4, l16 = lane & 15;
    int rowbase = blockIdx.x * 64 + wave * 16;
    int row = rowbase + l16;

    f32x4 acc[NT];
    f32x4 zero4 = {0.f, 0.f, 0.f, 0.f};
    #pragma unroll
    for (int nt = 0; nt < NT; nt++) acc[nt] = zero4;

    #pragma unroll
    for (int ks = 0; ks < 8; ks++) {
        int k0 = ks * 32 + quad * 8;
        const _Float16* Asel = (k0 < 128) ? A0 : A1;
        int ka = k0 & 127;
        half8 af = {0, 0, 0, 0, 0, 0, 0, 0};
        if (row < M) af = *(const half8*)(Asel + (size_t)row * 128 + ka);
        #pragma unroll
        for (int nt = 0; nt < NT; nt++) {
            half8 bfr = Bf[(ks * NT + nt) * 64 + lane];
            acc[nt] = __builtin_amdgcn_mfma_f32_16x16x32_f16(af, bfr, acc[nt], 0, 0, 0);
        }
    }

    // all A-reads for this wave's 16-row band done; epilogue writes same band only
    #pragma unroll
    for (int nt = 0; nt < NT; nt++) {
        int col = nt * 16 + l16;
        float bv = brel[col] + blin[col];
        #pragma unroll
        for (int r = 0; r < 4; r++) {
            int rr = rowbase + quad * 4 + r;
            if (rr < M) {
                float v = acc[nt][r] + bv;
                v = (v >= 0.f) ? v : 0.01f * v;
                if (Cf) Cf[(size_t)rr * 128 + col] = v;
                Ch[(size_t)rr * 128 + col] = (_Float16)v;
            }
        }
    }
}

// ---- fc head GEMM, LDS-free: Y = A@W + b, N=64 ----
__global__ __launch_bounds__(256) void gemmfc_k(const _Float16* __restrict__ A,
                                                const half8* __restrict__ Bf,   // KS=4, NT=4
                                                const float* __restrict__ bias,
                                                float* __restrict__ C,
                                                int M) {
    constexpr int K = 128, N = 64, NT = 4;
    int tid = threadIdx.x;
    int wave = tid >> 6, lane = tid & 63;
    int quad = lane >> 4, l16 = lane & 15;
    int rowbase = blockIdx.x * 64 + wave * 16;
    int row = rowbase + l16;

    f32x4 acc[NT];
    f32x4 zero4 = {0.f, 0.f, 0.f, 0.f};
    #pragma unroll
    for (int nt = 0; nt < NT; nt++) acc[nt] = zero4;

    #pragma unroll
    for (int ks = 0; ks < 4; ks++) {
        int k0 = ks * 32 + quad * 8;
        half8 af = {0, 0, 0, 0, 0, 0, 0, 0};
        if (row < M) af = *(const half8*)(A + (size_t)row * K + k0);
        #pragma unroll
        for (int nt = 0; nt < NT; nt++) {
            half8 bfr = Bf[(ks * NT + nt) * 64 + lane];
            acc[nt] = __builtin_amdgcn_mfma_f32_16x16x32_f16(af, bfr, acc[nt], 0, 0, 0);
        }
    }

    #pragma unroll
    for (int nt = 0; nt < NT; nt++) {
        int col = nt * 16 + l16;
        float bv = bias[col];
        #pragma unroll
        for (int r = 0; r < 4; r++) {
            int rr = rowbase + quad * 4 + r;
            if (rr < M) C[(size_t)rr * N + col] = acc[nt][r] + bv;
        }
    }
}

extern "C" void kernel_launch(void* const* d_in, const int* in_sizes, int n_in,
                              void* d_out, int out_size, void* d_ws, size_t ws_size,
                              hipStream_t stream) {
    const float* X       = (const float*)d_in[0];
    const int*   EIX     = (const int*)d_in[1];
    const int*   HIX     = (const int*)d_in[2];
    const float* hc1_w   = (const float*)d_in[3];
    const float* hc1_b   = (const float*)d_in[4];
    const float* lin1_w  = (const float*)d_in[5];
    const float* lin1_b  = (const float*)d_in[6];
    const float* hc2_w   = (const float*)d_in[7];
    const float* hc2_b   = (const float*)d_in[8];
    const float* lin2_w  = (const float*)d_in[9];
    const float* lin2_b  = (const float*)d_in[10];
    const float* c1_wrel = (const float*)d_in[11];
    const float* c1_brel = (const float*)d_in[12];
    const float* c1_wroot= (const float*)d_in[13];
    const float* glin1_w = (const float*)d_in[14];
    const float* glin1_b = (const float*)d_in[15];
    const float* c2_wrel = (const float*)d_in[16];
    const float* c2_brel = (const float*)d_in[17];
    const float* c2_wroot= (const float*)d_in[18];
    const float* glin2_w = (const float*)d_in[19];
    const float* glin2_b = (const float*)d_in[20];
    const float* fc_w    = (const float*)d_in[21];
    const float* fc_b    = (const float*)d_in[22];

    // ---- workspace carve (~48 MB; ws is 256 MiB per round-5 poison-fill counter) ----
    char* wsp = (char*)d_ws;
    size_t off = 0;
    auto carve = [&](size_t bytes) -> char* {
        char* p = wsp + off;
        off = (off + bytes + 255) & ~(size_t)255;
        return p;
    };
    int*   flags  = (int*)carve(16);
    int*   counts = (int*)carve(110000 * 4);
    int*   offs   = (int*)carve(110003 * 4);
    int*   bsums  = (int*)carve(192 * 4);
    int*   bcur   = (int*)carve(3 * NBK * 4);
    u16*   vals   = (u16*)carve(2400000 * 2);
    _Float16* F   = (_Float16*)carve((4 * 32768 + 8192) * 2);   // frag-ordered weights, 272 KB
    // union: packed pairs (3*NBK*BKCAP*4 = 12.6MB, dead after unbin) vs P+L (25.6MB)
    char*  U      = carve((size_t)NN * 128 * 2 * 2);
    _Float16* P  = (_Float16*)U;                            // 12.8 MB
    _Float16* L  = (_Float16*)(U + (size_t)NN * 128 * 2);   // 12.8 MB
    unsigned* pairs = (unsigned*)U;
    _Float16* MH = (_Float16*)carve((size_t)HECNT * 128 * 2);  // 2.56 MB
    _Float16* XA = (_Float16*)carve((size_t)NN * 128 * 2);     // 12.8 MB f16 chain

    float* XO = (float*)d_out;                 // final X: 50000 x 128 f32
    float* YO = XO + (size_t)NN * 128;         // final y: 50000 x 64 f32

    const half8* F0 = (const half8*)F;                     // L1 [hc1|lin1]
    const half8* F1 = (const half8*)(F + 32768);           // L2
    const half8* F2 = (const half8*)(F + 2 * 32768);       // L3
    const half8* F3 = (const half8*)(F + 3 * 32768);       // L4
    const half8* F4 = (const half8*)(F + 4 * 32768);       // fc

    // ---- CSR build + weight prep (19 dispatches total) ----
    detect_binit_k<<<2, 256, 0, stream>>>(EIX, HIX, flags, bcur);
    wprep_k<<<dim3(16, 5), 256, 0, stream>>>(hc1_w, lin1_w, hc2_w, lin2_w,
                                             c1_wrel, c1_wroot, glin1_w,
                                             c2_wrel, c2_wroot, glin2_w, fc_w, F);
    bin01_k<<<(II + CHUNK - 1) / CHUNK, 256, 0, stream>>>(HIX, flags, bcur, pairs);
    bin2_k<<<(EE + CHUNK - 1) / CHUNK, 256, 0, stream>>>(EIX, flags, bcur, pairs);
    count_k<<<3 * NBK, 256, 0, stream>>>(bcur, pairs, counts);
    scan_p1<<<dim3(49, 3), 256, 0, stream>>>(counts, bsums);
    scan_p2<<<dim3(1, 3), 64, 0, stream>>>(bsums, offs);
    scan_p3<<<dim3(49, 3), 256, 0, stream>>>(counts, bsums, offs);
    unbin_k<<<3 * NBK, 256, 0, stream>>>(offs, pairs, vals);

    const int* offs_he   = offs;                    // [HECNT+1]
    const int* offs_node = offs + HECNT + 1;        // [NN+1]
    const int* offs_dst  = offs + HECNT + NN + 2;   // [NN+1]
    const u16* vals_he   = vals;
    const u16* vals_node = vals + 800000;
    const u16* vals_dst  = vals + 1600000;

    int g64 = (NN + 63) / 64;         // 782
    int ghe = (HECNT + 3) / 4;        // 2500
    int gnn = (NN + 3) / 4;           // 12500

    // ---- Layer 1: X1 = leaky(Dinv H Binv H^T (X@hc1) + hc1_b + X@lin1 + lin1_b) ----
    gemm2_k<float><<<g64, 256, 0, stream>>>(X, F0, lin1_b, P, L, NN);
    gather_k<<<ghe, 256, 0, stream>>>(offs_he, vals_he, P, MH, HECNT, NN, 1, nullptr, nullptr, 0);
    gather_k<<<gnn, 256, 0, stream>>>(offs_node, vals_node, MH, XA, NN, HECNT, 1, hc1_b, L, 1);

    // ---- Layer 2 ----
    gemm2_k<_Float16><<<g64, 256, 0, stream>>>(XA, F1, lin2_b, P, L, NN);
    gather_k<<<ghe, 256, 0, stream>>>(offs_he, vals_he, P, MH, HECNT, NN, 1, nullptr, nullptr, 0);
    gather_k<<<gnn, 256, 0, stream>>>(offs_node, vals_node, MH, XA, NN, HECNT, 1, hc2_b, L, 1);   // XA = X2

    // ---- Layer 3: X3 = leaky([AGG|X2] @ [Wrel; Wroot+glin1] + brel + glin1_b) ----
    gather_k<<<gnn, 256, 0, stream>>>(offs_dst, vals_dst, XA, P, NN, NN, 0, nullptr, nullptr, 0); // P = AGG
    gemmk2_k<<<g64, 256, 0, stream>>>(P, XA, F2, c1_brel, glin1_b, nullptr, XA, NN);              // XA = X3

    // ---- Layer 4: X4 → XO (f32) + XA (f16 for fc) ----
    gather_k<<<gnn, 256, 0, stream>>>(offs_dst, vals_dst, XA, P, NN, NN, 0, nullptr, nullptr, 0);
    gemmk2_k<<<g64, 256, 0, stream>>>(P, XA, F3, c2_brel, glin2_b, XO, XA, NN);

    // ---- fc head ----
    gemmfc_k<<<g64, 256, 0, stream>>>(XA, F4, fc_b, YO, NN);
}

// Round 9
// 477.735 us; speedup vs baseline: 1.0636x; 1.0636x over previous
//
#include <hip/hip_runtime.h>

#define NN 50000
#define HECNT 10000
#define EE 800000
#define II 800000
#define NBK 128          // buckets per task (counting sort)
#define CHUNK 4096       // edges per workgroup in bin_k
#define BKCAP 8192       // fixed staging capacity per bucket (mean 6250, +24 sigma)

typedef _Float16 half8 __attribute__((ext_vector_type(8)));
typedef float f32x4    __attribute__((ext_vector_type(4)));
typedef unsigned short u16;

__device__ __forceinline__ int ld_idx(const int* p, long long pos, int is64) {
    return is64 ? p[pos * 2] : p[(int)pos];
}

__device__ __forceinline__ void task_info(int t, int& n, int& cbase, int& obase) {
    if (t == 0)      { n = HECNT; cbase = 0;           obase = 0; }
    else if (t == 1) { n = NN;    cbase = HECNT;       obase = HECNT + 1; }
    else             { n = NN;    cbase = HECNT + NN;  obase = HECNT + NN + 2; }
}

// load (dest, val) for incidence/edge i of task t; dest<0 if invalid
__device__ __forceinline__ void ld_edge(int t, long long i,
                                        const int* EIX, const int* HIX,
                                        int f0, int f1, int& d, int& v) {
    int rng;
    if (t == 0)      { d = ld_idx(HIX, (long long)II + i, f1); v = ld_idx(HIX, i, f1); rng = HECNT; }
    else if (t == 1) { d = ld_idx(HIX, i, f1); v = ld_idx(HIX, (long long)II + i, f1); rng = NN; }
    else             { d = ld_idx(EIX, (long long)EE + i, f0); v = ld_idx(EIX, i, f0); rng = NN; }
    if ((unsigned)d >= (unsigned)rng || (unsigned)v >= 65536u) d = -1;
}

// ---------------- detect index width + init bucket cursors ----------------
__global__ void detect_binit_k(const int* __restrict__ EIX, const int* __restrict__ HIX,
                               int* __restrict__ flags, int* __restrict__ bcur) {
    int tid = threadIdx.x;
    int i = blockIdx.x * 256 + tid;
    if (i < 3 * NBK) bcur[i] = i * BKCAP;
    if (blockIdx.x == 0) {
        __shared__ int o0, o1;
        if (tid == 0) { o0 = 0; o1 = 0; }
        __syncthreads();
        atomicOr(&o0, EIX[2 * tid + 1]);
        atomicOr(&o1, HIX[2 * tid + 1]);
        __syncthreads();
        if (tid == 0) { flags[0] = (o0 == 0); flags[1] = (o1 == 0); }
    }
}

// ---- bucket-bin all 3 tasks (blockIdx.y = task), fixed-capacity staging, packed u32 pairs ----
__global__ __launch_bounds__(256) void bin_k(const int* __restrict__ EIX,
                                             const int* __restrict__ HIX,
                                             const int* __restrict__ flags,
                                             int* __restrict__ bcur,
                                             unsigned* __restrict__ pairs) {
    int t = blockIdx.y;
    __shared__ int hcnt[NBK], hstart[NBK], hrun[NBK], gbase[NBK];
    __shared__ int stot;
    __shared__ unsigned stage[CHUNK];    // 16 KB
    int tid = threadIdx.x;
    int n, cb, ob; task_info(t, n, cb, ob);
    int span = (n + NBK - 1) / NBK;
    long long base = (long long)blockIdx.x * CHUNK;
    int f0 = flags[0], f1 = flags[1];

    for (int i = tid; i < NBK; i += 256) { hcnt[i] = 0; hrun[i] = 0; }
    __syncthreads();

    int d[16], v[16];
    #pragma unroll
    for (int j = 0; j < 16; j++) {
        long long i = base + j * 256 + tid;
        int dd = -1, vv = 0;
        if (i < EE) ld_edge(t, i, EIX, HIX, f0, f1, dd, vv);
        d[j] = dd; v[j] = vv;
        if (dd >= 0) atomicAdd(&hcnt[dd / span], 1);
    }
    __syncthreads();

    if (tid < NBK) gbase[tid] = hcnt[tid] ? atomicAdd(&bcur[t * NBK + tid], hcnt[tid]) : 0;
    if (tid < NBK) hstart[tid] = hcnt[tid];
    __syncthreads();
    for (int o = 1; o < NBK; o <<= 1) {
        int u = 0;
        if (tid < NBK && tid >= o) u = hstart[tid - o];
        __syncthreads();
        if (tid < NBK) hstart[tid] += u;
        __syncthreads();
    }
    if (tid == NBK - 1) stot = hstart[tid];
    __syncthreads();
    if (tid < NBK) hstart[tid] -= hcnt[tid];   // exclusive
    __syncthreads();

    #pragma unroll
    for (int j = 0; j < 16; j++) {
        if (d[j] >= 0) {
            int b = d[j] / span;
            int p = hstart[b] + atomicAdd(&hrun[b], 1);
            stage[p] = ((unsigned)d[j] << 16) | (unsigned)v[j];
        }
    }
    __syncthreads();

    int total = stot;
    for (int i = tid; i < total; i += 256) {
        int lo = 0, hi = NBK - 1;                  // last bucket with hstart <= i
        while (lo < hi) { int mid = (lo + hi + 1) >> 1; if (hstart[mid] <= i) lo = mid; else hi = mid - 1; }
        int pos = gbase[lo] + (i - hstart[lo]);
        if (pos < (t * NBK + lo + 1) * BKCAP)      // capacity clamp (never expected)
            pairs[pos] = stage[lo == 0 ? i : i];   // stage[i]
    }
}

// ---- task-local exclusive prefix over 384 bucket counts (1 block) ----
__global__ __launch_bounds__(384) void bscan_k(const int* __restrict__ bcur,
                                               int* __restrict__ bbase,
                                               int* __restrict__ offs) {
    __shared__ int sc[3 * NBK];
    int tid = threadIdx.x;              // 0..383
    int c = 0;
    if (tid < 3 * NBK) {
        c = bcur[tid] - tid * BKCAP;
        c = max(0, min(c, BKCAP));
        sc[tid] = c;
    }
    __syncthreads();
    int b = tid & (NBK - 1);
    for (int o = 1; o < NBK; o <<= 1) {
        int u = 0;
        if (tid < 3 * NBK && b >= o) u = sc[tid - o];
        __syncthreads();
        if (tid < 3 * NBK) sc[tid] += u;
        __syncthreads();
    }
    if (tid < 3 * NBK) {
        bbase[tid] = sc[tid] - c;        // task-local exclusive
        if (b == NBK - 1) {              // task total -> CSR sentinel
            int t = tid >> 7;
            int n, cb, ob; task_info(t, n, cb, ob);
            offs[ob + n] = sc[tid];
        }
    }
}

// ---- per-bucket finisher: hist + prefix + offs write + exact placement + u16 flush ----
__global__ __launch_bounds__(256) void bfin_k(const int* __restrict__ bcur,
                                              const int* __restrict__ bbase,
                                              const unsigned* __restrict__ pairs,
                                              int* __restrict__ offs,
                                              u16* __restrict__ vals) {
    int idx = blockIdx.x;              // 0 .. 3*NBK-1
    int t = idx / NBK, b = idx % NBK;
    int n, cb, ob; task_info(t, n, cb, ob);
    int span = (n + NBK - 1) / NBK;
    int dlo = min(b * span, n), dhi = min(dlo + span, n);
    if (dhi <= dlo) return;
    int nd = dhi - dlo;                // <= 391
    int cnt = bcur[idx] - idx * BKCAP;
    cnt = max(0, min(cnt, BKCAP));
    int base = bbase[idx];

    __shared__ int hist[512], sc[512], cur[400];
    __shared__ u16 win[BKCAP];         // 16 KB
    int tid = threadIdx.x;
    for (int i = tid; i < 512; i += 256) { hist[i] = 0; }
    __syncthreads();

    const unsigned* pw = pairs + (size_t)idx * BKCAP;
    for (int i = tid; i < cnt; i += 256) {
        int dl = (int)(pw[i] >> 16) - dlo;
        if ((unsigned)dl < (unsigned)nd) atomicAdd(&hist[dl], 1);
    }
    __syncthreads();

    // inclusive Hillis-Steele over 512 (2 elems/thread)
    int s0 = tid, s1 = tid + 256;
    sc[s0] = hist[s0]; sc[s1] = hist[s1];
    __syncthreads();
    for (int o = 1; o < 512; o <<= 1) {
        int u0 = (s0 >= o) ? sc[s0 - o] : 0;
        int u1 = (s1 >= o) ? sc[s1 - o] : 0;
        __syncthreads();
        sc[s0] += u0; sc[s1] += u1;
        __syncthreads();
    }
    // exclusive prefix, offs write (coalesced), local cursors
    for (int i = tid; i < nd; i += 256) {
        int ex = sc[i] - hist[i];
        offs[ob + dlo + i] = base + ex;
        cur[i] = ex;
    }
    __syncthreads();

    for (int i = tid; i < cnt; i += 256) {
        unsigned pv = pw[i];
        int dl = (int)(pv >> 16) - dlo;
        if ((unsigned)dl < (unsigned)nd) {
            int p = atomicAdd(&cur[dl], 1);
            if ((unsigned)p < (unsigned)BKCAP) win[p] = (u16)(pv & 0xffffu);
        }
    }
    __syncthreads();
    u16* vw = vals + (size_t)t * 800000 + base;
    for (int i = tid; i < cnt; i += 256) vw[i] = win[i];
}

// ------- gather: 1 dest/wave, 16 lanes x half8, 16 rows in flight/wave; epilogue finishes the layer -------
__global__ __launch_bounds__(256) void gather_k(const int* __restrict__ offs,
                                                const u16* __restrict__ vals,
                                                const _Float16* __restrict__ src,   // [S x 128] f16
                                                _Float16* __restrict__ out,         // [ndst x 128] f16
                                                int ndst, int nsrc, int scale_flag,
                                                const float* __restrict__ bias,
                                                const _Float16* __restrict__ addend,
                                                int act) {
    int wave = threadIdx.x >> 6, lane = threadIdx.x & 63;
    int sub = lane >> 4, l16 = lane & 15;
    int d = blockIdx.x * 4 + wave;
    if (d >= ndst) return;
    int beg = offs[d], end = offs[d + 1];
    int f = l16 * 8;
    float a[8] = {0.f, 0.f, 0.f, 0.f, 0.f, 0.f, 0.f, 0.f};
    auto acc_row = [&](int s) {
        if ((unsigned)s < (unsigned)nsrc) {
            half8 u = *(const half8*)(src + (size_t)s * 128 + f);
            #pragma unroll
            for (int j = 0; j < 8; j++) a[j] += (float)u[j];
        }
    };
    int e = beg + sub;
    for (; e + 12 < end; e += 16) {          // 4 rows in flight per sub, 16 per wave
        int s0 = vals[e], s1 = vals[e + 4], s2 = vals[e + 8], s3 = vals[e + 12];
        acc_row(s0); acc_row(s1); acc_row(s2); acc_row(s3);
    }
    for (; e < end; e += 4) acc_row(vals[e]);
    #pragma unroll
    for (int j = 0; j < 8; j++) {
        a[j] += __shfl_xor(a[j], 16, 64);
        a[j] += __shfl_xor(a[j], 32, 64);
    }
    if (sub == 0) {
        if (scale_flag) {
            int c = end - beg;
            float iv = (c > 0) ? 1.f / (float)c : 0.f;
            #pragma unroll
            for (int j = 0; j < 8; j++) a[j] *= iv;
        }
        if (bias) {
            f32x4 b0 = *(const f32x4*)(bias + f);
            f32x4 b1 = *(const f32x4*)(bias + f + 4);
            #pragma unroll
            for (int j = 0; j < 4; j++) { a[j] += b0[j]; a[4 + j] += b1[j]; }
        }
        if (addend) {
            half8 u = *(const half8*)(addend + (size_t)d * 128 + f);
            #pragma unroll
            for (int j = 0; j < 8; j++) a[j] += (float)u[j];
        }
        if (act) {
            #pragma unroll
            for (int j = 0; j < 8; j++) a[j] = (a[j] >= 0.f) ? a[j] : 0.01f * a[j];
        }
        half8 o;
        #pragma unroll
        for (int j = 0; j < 8; j++) o[j] = (_Float16)a[j];
        *(half8*)(out + (size_t)d * 128 + f) = o;
    }
}

// ---- one-time weight prep: write W in MFMA B-fragment order (half8 per lane) ----
__global__ __launch_bounds__(256) void wprep_k(const float* __restrict__ hc1_w, const float* __restrict__ lin1_w,
                                               const float* __restrict__ hc2_w, const float* __restrict__ lin2_w,
                                               const float* __restrict__ c1_wrel, const float* __restrict__ c1_wroot,
                                               const float* __restrict__ glin1_w,
                                               const float* __restrict__ c2_wrel, const float* __restrict__ c2_wroot,
                                               const float* __restrict__ glin2_w,
                                               const float* __restrict__ fc_w,
                                               _Float16* __restrict__ F) {
    int set = blockIdx.y;
    int nfrag = (set == 4) ? 1024 : 4096;   // # of half8 fragments
    int NT = (set < 2) ? 16 : (set == 4 ? 4 : 8);
    int fid = blockIdx.x * 256 + threadIdx.x;
    if (fid >= nfrag) return;
    int lane = fid & 63;
    int tile = fid >> 6;                    // ks*NT + nt
    int nt = tile % NT, ks = tile / NT;
    int n = nt * 16 + (lane & 15);
    int kbase = ks * 32 + (lane >> 4) * 8;
    _Float16* dst = F + (size_t)set * 32768 + (size_t)fid * 8;
    #pragma unroll
    for (int j = 0; j < 8; j++) {
        int k = kbase + j;
        float w;
        if (set == 0)      w = (n < 128) ? hc1_w[k * 128 + n] : lin1_w[k * 128 + n - 128];
        else if (set == 1) w = (n < 128) ? hc2_w[k * 128 + n] : lin2_w[k * 128 + n - 128];
        else if (set == 2) w = (k < 128) ? c1_wrel[k * 128 + n]
                                         : c1_wroot[(k - 128) * 128 + n] + glin1_w[(k - 128) * 128 + n];
        else if (set == 3) w = (k < 128) ? c2_wrel[k * 128 + n]
                                         : c2_wroot[(k - 128) * 128 + n] + glin2_w[(k - 128) * 128 + n];
        else               w = fc_w[k * 64 + n];
        dst[j] = (_Float16)w;
    }
}

// ---- dual-output GEMM, LDS-free: P = A@W1, L = A@W2 + b2. B-frags from global (L2-hot). ----
template <typename AT>
__global__ __launch_bounds__(256) void gemm2_k(const AT* __restrict__ A,
                                               const half8* __restrict__ Bf,   // KS=4, NT=16
                                               const float* __restrict__ b2,
                                               _Float16* __restrict__ O1,
                                               _Float16* __restrict__ O2,
                                               int M) {
    constexpr int K = 128, NT = 16;
    int tid = threadIdx.x;
    int wave = tid >> 6, lane = tid & 63;
    int quad = lane >> 4, l16 = lane & 15;
    int rowbase = blockIdx.x * 64 + wave * 16;
    int row = rowbase + l16;

    f32x4 acc[NT];
    f32x4 zero4 = {0.f, 0.f, 0.f, 0.f};
    #pragma unroll
    for (int nt = 0; nt < NT; nt++) acc[nt] = zero4;

    #pragma unroll
    for (int ks = 0; ks < 4; ks++) {
        int k0 = ks * 32 + quad * 8;
        half8 af = {0, 0, 0, 0, 0, 0, 0, 0};
        if (row < M) {
            if constexpr (sizeof(AT) == 4) {
                const float* ap = (const float*)A + (size_t)row * K + k0;
                float4 x0 = *(const float4*)ap;
                float4 x1 = *(const float4*)(ap + 4);
                af = half8{(_Float16)x0.x, (_Float16)x0.y, (_Float16)x0.z, (_Float16)x0.w,
                           (_Float16)x1.x, (_Float16)x1.y, (_Float16)x1.z, (_Float16)x1.w};
            } else {
                af = *(const half8*)((const _Float16*)A + (size_t)row * K + k0);
            }
        }
        #pragma unroll
        for (int nt = 0; nt < NT; nt++) {
            half8 bfr = Bf[(ks * NT + nt) * 64 + lane];
            acc[nt] = __builtin_amdgcn_mfma_f32_16x16x32_f16(af, bfr, acc[nt], 0, 0, 0);
        }
    }

    #pragma unroll
    for (int nt = 0; nt < NT; nt++) {
        int col = nt * 16 + l16;
        bool second = (col >= 128);
        int c = second ? col - 128 : col;
        float bv = second ? b2[c] : 0.f;
        _Float16* O = second ? O2 : O1;
        #pragma unroll
        for (int r = 0; r < 4; r++) {
            int rr = rowbase + quad * 4 + r;
            if (rr < M) O[(size_t)rr * 128 + c] = (_Float16)(acc[nt][r] + bv);
        }
    }
}

// ---- K=256 GEMM, LDS-free: out = leaky(A0@Wrel + A1@(Wroot+Wlin) + brel + blin) ----
__global__ __launch_bounds__(256) void gemmk2_k(const _Float16* __restrict__ A0,
                                                const _Float16* A1,
                                                const half8* __restrict__ Bf,   // KS=8, NT=8
                                                const float* __restrict__ brel,
                                                const float* __restrict__ blin,
                                                float* __restrict__ Cf,    // optional f32 out
                                                _Float16* Ch,              // f16 out (may alias A1)
                                                int M) {
    constexpr int NT = 8;
    int tid = threadIdx.x;
    int wave = tid >> 6, lane = tid & 63;
    int quad = lane >> 4, l16 = lane & 15;
    int rowbase = blockIdx.x * 64 + wave * 16;
    int row = rowbase + l16;

    f32x4 acc[NT];
    f32x4 zero4 = {0.f, 0.f, 0.f, 0.f};
    #pragma unroll
    for (int nt = 0; nt < NT; nt++) acc[nt] = zero4;

    #pragma unroll
    for (int ks = 0; ks < 8; ks++) {
        int k0 = ks * 32 + quad * 8;
        const _Float16* Asel = (k0 < 128) ? A0 : A1;
        int ka = k0 & 127;
        half8 af = {0, 0, 0, 0, 0, 0, 0, 0};
        if (row < M) af = *(const half8*)(Asel + (size_t)row * 128 + ka);
        #pragma unroll
        for (int nt = 0; nt < NT; nt++) {
            half8 bfr = Bf[(ks * NT + nt) * 64 + lane];
            acc[nt] = __builtin_amdgcn_mfma_f32_16x16x32_f16(af, bfr, acc[nt], 0, 0, 0);
        }
    }

    // all A-reads for this wave's 16-row band done; epilogue writes same band only
    #pragma unroll
    for (int nt = 0; nt < NT; nt++) {
        int col = nt * 16 + l16;
        float bv = brel[col] + blin[col];
        #pragma unroll
        for (int r = 0; r < 4; r++) {
            int rr = rowbase + quad * 4 + r;
            if (rr < M) {
                float v = acc[nt][r] + bv;
                v = (v >= 0.f) ? v : 0.01f * v;
                if (Cf) Cf[(size_t)rr * 128 + col] = v;
                Ch[(size_t)rr * 128 + col] = (_Float16)v;
            }
        }
    }
}

// ---- fc head GEMM, LDS-free: Y = A@W + b, N=64 ----
__global__ __launch_bounds__(256) void gemmfc_k(const _Float16* __restrict__ A,
                                                const half8* __restrict__ Bf,   // KS=4, NT=4
                                                const float* __restrict__ bias,
                                                float* __restrict__ C,
                                                int M) {
    constexpr int K = 128, N = 64, NT = 4;
    int tid = threadIdx.x;
    int wave = tid >> 6, lane = tid & 63;
    int quad = lane >> 4, l16 = lane & 15;
    int rowbase = blockIdx.x * 64 + wave * 16;
    int row = rowbase + l16;

    f32x4 acc[NT];
    f32x4 zero4 = {0.f, 0.f, 0.f, 0.f};
    #pragma unroll
    for (int nt = 0; nt < NT; nt++) acc[nt] = zero4;

    #pragma unroll
    for (int ks = 0; ks < 4; ks++) {
        int k0 = ks * 32 + quad * 8;
        half8 af = {0, 0, 0, 0, 0, 0, 0, 0};
        if (row < M) af = *(const half8*)(A + (size_t)row * K + k0);
        #pragma unroll
        for (int nt = 0; nt < NT; nt++) {
            half8 bfr = Bf[(ks * NT + nt) * 64 + lane];
            acc[nt] = __builtin_amdgcn_mfma_f32_16x16x32_f16(af, bfr, acc[nt], 0, 0, 0);
        }
    }

    #pragma unroll
    for (int nt = 0; nt < NT; nt++) {
        int col = nt * 16 + l16;
        float bv = bias[col];
        #pragma unroll
        for (int r = 0; r < 4; r++) {
            int rr = rowbase + quad * 4 + r;
            if (rr < M) C[(size_t)rr * N + col] = acc[nt][r] + bv;
        }
    }
}

extern "C" void kernel_launch(void* const* d_in, const int* in_sizes, int n_in,
                              void* d_out, int out_size, void* d_ws, size_t ws_size,
                              hipStream_t stream) {
    const float* X       = (const float*)d_in[0];
    const int*   EIX     = (const int*)d_in[1];
    const int*   HIX     = (const int*)d_in[2];
    const float* hc1_w   = (const float*)d_in[3];
    const float* hc1_b   = (const float*)d_in[4];
    const float* lin1_w  = (const float*)d_in[5];
    const float* lin1_b  = (const float*)d_in[6];
    const float* hc2_w   = (const float*)d_in[7];
    const float* hc2_b   = (const float*)d_in[8];
    const float* lin2_w  = (const float*)d_in[9];
    const float* lin2_b  = (const float*)d_in[10];
    const float* c1_wrel = (const float*)d_in[11];
    const float* c1_brel = (const float*)d_in[12];
    const float* c1_wroot= (const float*)d_in[13];
    const float* glin1_w = (const float*)d_in[14];
    const float* glin1_b = (const float*)d_in[15];
    const float* c2_wrel = (const float*)d_in[16];
    const float* c2_brel = (const float*)d_in[17];
    const float* c2_wroot= (const float*)d_in[18];
    const float* glin2_w = (const float*)d_in[19];
    const float* glin2_b = (const float*)d_in[20];
    const float* fc_w    = (const float*)d_in[21];
    const float* fc_b    = (const float*)d_in[22];

    // ---- workspace carve (~47 MB; ws is 256 MiB per round-5 poison-fill counter) ----
    char* wsp = (char*)d_ws;
    size_t off = 0;
    auto carve = [&](size_t bytes) -> char* {
        char* p = wsp + off;
        off = (off + bytes + 255) & ~(size_t)255;
        return p;
    };
    int*   flags  = (int*)carve(16);
    int*   offs   = (int*)carve(110003 * 4);
    int*   bcur   = (int*)carve(3 * NBK * 4);
    int*   bbase  = (int*)carve(3 * NBK * 4);
    u16*   vals   = (u16*)carve(2400000 * 2);
    _Float16* F   = (_Float16*)carve((4 * 32768 + 8192) * 2);   // frag-ordered weights, 272 KB
    // union: packed pairs (3*NBK*BKCAP*4 = 12.6MB, dead after bfin) vs P+L (25.6MB)
    char*  U      = carve((size_t)NN * 128 * 2 * 2);
    _Float16* P  = (_Float16*)U;                            // 12.8 MB
    _Float16* L  = (_Float16*)(U + (size_t)NN * 128 * 2);   // 12.8 MB
    unsigned* pairs = (unsigned*)U;
    _Float16* MH = (_Float16*)carve((size_t)HECNT * 128 * 2);  // 2.56 MB
    _Float16* XA = (_Float16*)carve((size_t)NN * 128 * 2);     // 12.8 MB f16 chain

    float* XO = (float*)d_out;                 // final X: 50000 x 128 f32
    float* YO = XO + (size_t)NN * 128;         // final y: 50000 x 64 f32

    const half8* F0 = (const half8*)F;                     // L1 [hc1|lin1]
    const half8* F1 = (const half8*)(F + 32768);           // L2
    const half8* F2 = (const half8*)(F + 2 * 32768);       // L3
    const half8* F3 = (const half8*)(F + 3 * 32768);       // L4
    const half8* F4 = (const half8*)(F + 4 * 32768);       // fc

    // ---- CSR build + weight prep (5 dispatches) ----
    detect_binit_k<<<2, 256, 0, stream>>>(EIX, HIX, flags, bcur);
    wprep_k<<<dim3(16, 5), 256, 0, stream>>>(hc1_w, lin1_w, hc2_w, lin2_w,
                                             c1_wrel, c1_wroot, glin1_w,
                                             c2_wrel, c2_wroot, glin2_w, fc_w, F);
    bin_k<<<dim3((EE + CHUNK - 1) / CHUNK, 3), 256, 0, stream>>>(EIX, HIX, flags, bcur, pairs);
    bscan_k<<<1, 384, 0, stream>>>(bcur, bbase, offs);
    bfin_k<<<3 * NBK, 256, 0, stream>>>(bcur, bbase, pairs, offs, vals);

    const int* offs_he   = offs;                    // [HECNT+1]
    const int* offs_node = offs + HECNT + 1;        // [NN+1]
    const int* offs_dst  = offs + HECNT + NN + 2;   // [NN+1]
    const u16* vals_he   = vals;
    const u16* vals_node = vals + 800000;
    const u16* vals_dst  = vals + 1600000;

    int g64 = (NN + 63) / 64;         // 782
    int ghe = (HECNT + 3) / 4;        // 2500
    int gnn = (NN + 3) / 4;           // 12500

    // ---- Layer 1: X1 = leaky(Dinv H Binv H^T (X@hc1) + hc1_b + X@lin1 + lin1_b) ----
    gemm2_k<float><<<g64, 256, 0, stream>>>(X, F0, lin1_b, P, L, NN);
    gather_k<<<ghe, 256, 0, stream>>>(offs_he, vals_he, P, MH, HECNT, NN, 1, nullptr, nullptr, 0);
    gather_k<<<gnn, 256, 0, stream>>>(offs_node, vals_node, MH, XA, NN, HECNT, 1, hc1_b, L, 1);

    // ---- Layer 2 ----
    gemm2_k<_Float16><<<g64, 256, 0, stream>>>(XA, F1, lin2_b, P, L, NN);
    gather_k<<<ghe, 256, 0, stream>>>(offs_he, vals_he, P, MH, HECNT, NN, 1, nullptr, nullptr, 0);
    gather_k<<<gnn, 256, 0, stream>>>(offs_node, vals_node, MH, XA, NN, HECNT, 1, hc2_b, L, 1);   // XA = X2

    // ---- Layer 3: X3 = leaky([AGG|X2] @ [Wrel; Wroot+glin1] + brel + glin1_b) ----
    gather_k<<<gnn, 256, 0, stream>>>(offs_dst, vals_dst, XA, P, NN, NN, 0, nullptr, nullptr, 0); // P = AGG
    gemmk2_k<<<g64, 256, 0, stream>>>(P, XA, F2, c1_brel, glin1_b, nullptr, XA, NN);              // XA = X3

    // ---- Layer 4: X4 → XO (f32) + XA (f16 for fc) ----
    gather_k<<<gnn, 256, 0, stream>>>(offs_dst, vals_dst, XA, P, NN, NN, 0, nullptr, nullptr, 0);
    gemmk2_k<<<g64, 256, 0, stream>>>(P, XA, F3, c2_brel, glin2_b, XO, XA, NN);

    // ---- fc head ----
    gemmfc_k<<<g64, 256, 0, stream>>>(XA, F4, fc_b, YO, NN);
}